// Round 11
// baseline (286.168 us; speedup 1.0000x reference)
//
#include <hip/hip_runtime.h>
#include <math.h>

#define HID 1024
#define NH  16
#define HD  64
#define NB  4
#define SL  2048
#define MROWS (NB * SL)   // 8192

typedef __attribute__((ext_vector_type(8))) short short8;
typedef __attribute__((ext_vector_type(4))) float f32x4;
typedef unsigned short ushort_t;
typedef unsigned int uint_t;

// fp32 -> bf16 bits, round-to-nearest-even
__device__ __forceinline__ uint_t f2bf(float x) {
    union { float f; uint_t u; } a; a.f = x;
    return (a.u + 0x7fffu + ((a.u >> 16) & 1u)) >> 16;
}

// async global->LDS, 16B per lane; LDS dest = wave-uniform base + lane*16
__device__ __forceinline__ void load_lds16(const void* g, void* l) {
    __builtin_amdgcn_global_load_lds(
        (const __attribute__((address_space(1))) void*)g,
        (__attribute__((address_space(3))) void*)l, 16, 0, 0);
}

// ---------------------------------------------------------------------------
// GEMM core: C(128x128) = A @ B^T, bf16, BK=64 (16 k-iters, 32 MFMA/wave/iter).
// LDS rows are 128 B = exactly 32 banks (row drops out of bank equation);
// chunks XOR-swizzled with r&7 (== c&7 at read) -> fragment b128 reads spread
// evenly over the 8 bank-groups.
// ---------------------------------------------------------------------------
__device__ __forceinline__ void gemm_core_bk64(
    const ushort_t* __restrict__ A, const ushort_t* __restrict__ B,
    const int m0, const int n0, ushort_t* As, ushort_t* Bs, f32x4 (&acc)[4][4])
{
    const int tid = threadIdx.x;
    const int w = tid >> 6, lane = tid & 63;
    const int wm = (w & 1) << 6, wn = (w >> 1) << 6;
    const int c = lane & 15, quad = lane >> 4;

    for (int k0 = 0; k0 < HID; k0 += 64) {
        __syncthreads();
        #pragma unroll
        for (int rd = 0; rd < 4; ++rd) {
            const int g = rd * 4 + w;            // wave-uniform group 0..15
            const int idx = g * 64 + lane;       // 16B-chunk id, 0..1023
            const int r = idx >> 3, sc = idx & 7;
            const int dc = sc ^ (r & 7);         // fetch permuted chunk
            load_lds16(&A[(size_t)(m0 + r) * HID + k0 + dc * 8], As + g * 512);
            load_lds16(&B[(size_t)(n0 + r) * HID + k0 + dc * 8], Bs + g * 512);
        }
        __syncthreads();

        #pragma unroll
        for (int ks = 0; ks < 2; ++ks) {
            short8 af[4], bf[4];
            #pragma unroll
            for (int i = 0; i < 4; ++i) {
                const int ra = wm + i * 16 + c;
                const int rb = wn + i * 16 + c;
                af[i] = *(const short8*)
                    &As[ra * 64 + ((((ks << 2) + quad) ^ (c & 7)) << 3)];
                bf[i] = *(const short8*)
                    &Bs[rb * 64 + ((((ks << 2) + quad) ^ (c & 7)) << 3)];
            }
            #pragma unroll
            for (int i = 0; i < 4; ++i)
                #pragma unroll
                for (int j = 0; j < 4; ++j)
                    acc[i][j] = __builtin_amdgcn_mfma_f32_16x16x32_bf16(
                        af[i], bf[j], acc[i][j], 0, 0, 0);
        }
    }
}

// ---------------------------------------------------------------------------
// fp32 -> bf16 conversion: 12 segments of 1M elems (x = 8 segs, 4 weights)
// ---------------------------------------------------------------------------
__global__ __launch_bounds__(256) void cvt_bf16_kernel(
    const float* __restrict__ x,
    const float* __restrict__ wq, const float* __restrict__ wk,
    const float* __restrict__ wv, const float* __restrict__ wo,
    ushort_t* __restrict__ xb, ushort_t* __restrict__ wqb,
    ushort_t* __restrict__ wkb, ushort_t* __restrict__ wvb,
    ushort_t* __restrict__ wob)
{
    const int seg = blockIdx.y;
    const float* src; ushort_t* dst;
    if (seg < 8)       { src = x + (size_t)seg * 1048576; dst = xb + (size_t)seg * 1048576; }
    else if (seg == 8) { src = wq; dst = wqb; }
    else if (seg == 9) { src = wk; dst = wkb; }
    else if (seg == 10){ src = wv; dst = wvb; }
    else               { src = wo; dst = wob; }
    const int i = (blockIdx.x * 256 + threadIdx.x) * 8;
    const float4 a = *(const float4*)&src[i];
    const float4 b = *(const float4*)&src[i + 4];
    uint4 o;
    o.x = f2bf(a.x) | (f2bf(a.y) << 16);
    o.y = f2bf(a.z) | (f2bf(a.w) << 16);
    o.z = f2bf(b.x) | (f2bf(b.y) << 16);
    o.w = f2bf(b.z) | (f2bf(b.w) << 16);
    *(uint4*)&dst[i] = o;
}

// ---------------------------------------------------------------------------
// QKV projection. grid (8 n-tiles, 64 m-tiles, 3 weights); 128x128 tile.
// Q pre-scaled by 0.125*log2(e); K as (B,H,S,D); V^T as (B,H,D,S).
//
// XCD-banded block remap (kept -- R7 isolated the pipeline gain to this):
// flat=x+8y, xcd=flat&7, s=flat>>3 -> (ny = xcd*8 + s/8, nx = s%8): XCD j
// owns m-band [8j,8j+8) x all 8 n-tiles.  Per-XCD L2 working set = weight
// 2 MB + A-band 2 MB = 4 MB = L2; A reused 8x in-XCD.
// ---------------------------------------------------------------------------
__global__ __launch_bounds__(256) void qkv_mfma_kernel(
    const ushort_t* __restrict__ xb,
    const ushort_t* __restrict__ wqb, const ushort_t* __restrict__ wkb,
    const ushort_t* __restrict__ wvb,
    const float* __restrict__ bq, const float* __restrict__ bk,
    const float* __restrict__ bv,
    ushort_t* __restrict__ qo, ushort_t* __restrict__ ko,
    ushort_t* __restrict__ vo)
{
    __shared__ __align__(16) ushort_t As[128 * 64];   // 16 KB
    __shared__ __align__(16) ushort_t Bs[128 * 64];   // 16 KB

    const int wsel = blockIdx.z;
    const ushort_t* W    = (wsel == 0) ? wqb : (wsel == 1) ? wkb : wvb;
    const float*    bias = (wsel == 0) ? bq  : (wsel == 1) ? bk  : bv;

    const int flat = blockIdx.x + (blockIdx.y << 3);   // 0..511
    const int xcd = flat & 7, s = flat >> 3;
    const int m0 = ((xcd << 3) + (s >> 3)) * 128;
    const int n0 = (s & 7) * 128;

    f32x4 acc[4][4];
    const f32x4 zero = {0.f, 0.f, 0.f, 0.f};
    #pragma unroll
    for (int i = 0; i < 4; ++i)
        #pragma unroll
        for (int j = 0; j < 4; ++j) acc[i][j] = zero;

    gemm_core_bk64(xb, W, m0, n0, As, Bs, acc);

    const int tid = threadIdx.x;
    const int w = tid >> 6, lane = tid & 63;
    const int wm = (w & 1) << 6, wn = (w >> 1) << 6;
    const int c = lane & 15, quad = lane >> 4;
    // 0.125 (1/sqrt(64)) * log2(e): scores land in log2 domain
    const float qscale = (wsel == 0) ? 0.18033688f : 1.0f;

    #pragma unroll
    for (int j = 0; j < 4; ++j) {
        const int n_g = n0 + wn + j * 16 + c;
        const float bj = bias[n_g];
        const int h = n_g >> 6, d = n_g & 63;
        #pragma unroll
        for (int i = 0; i < 4; ++i) {
            const int mbase = m0 + wm + i * 16 + quad * 4;
            const int b = mbase >> 11;
            const int sbase = mbase & (SL - 1);
            if (wsel == 2) {
                ushort4 pk;
                pk.x = (ushort_t)f2bf(acc[i][j][0] + bj);
                pk.y = (ushort_t)f2bf(acc[i][j][1] + bj);
                pk.z = (ushort_t)f2bf(acc[i][j][2] + bj);
                pk.w = (ushort_t)f2bf(acc[i][j][3] + bj);
                *(ushort4*)&vo[(((size_t)(b * NH + h) * HD) + d) * SL + sbase] = pk;
            } else {
                ushort_t* dst = (wsel == 0) ? qo : ko;
                #pragma unroll
                for (int reg = 0; reg < 4; ++reg) {
                    const float v = (acc[i][j][reg] + bj) * qscale;
                    dst[(((size_t)(b * NH + h) * SL) + sbase + reg) * HD + d] =
                        (ushort_t)f2bf(v);
                }
            }
        }
    }
}

// ---------------------------------------------------------------------------
// MFMA flash attention -- R10-verified best (89.9us): setprio + mask-as-
// MFMA-C-init + ones-column row-sum.  UNCHANGED this round (control).
// ---------------------------------------------------------------------------
__global__ __launch_bounds__(256, 4) void attn_mfma_kernel(
    const ushort_t* __restrict__ q, const ushort_t* __restrict__ k,
    const ushort_t* __restrict__ vt, const int* __restrict__ mask,
    ushort_t* __restrict__ ao)
{
    __shared__ __align__(16) ushort_t Ks[64 * 64];    // 8 KB
    __shared__ __align__(16) ushort_t Vs[64 * 64];    // 8 KB
    __shared__ __align__(16) ushort_t Ps[128 * 64];   // 16 KB (swizzled)

    const int qt = blockIdx.x;    // 0..15
    const int bh = blockIdx.y;
    const int b = bh >> 4, h = bh & 15;
    const int tid = threadIdx.x;
    const int w = tid >> 6, lane = tid & 63;
    const int c = lane & 15, quad = lane >> 4;

    const ushort_t* qp = q  + (size_t)bh * SL * HD + (size_t)qt * 128 * HD;
    const ushort_t* kp = k  + (size_t)bh * SL * HD;
    const ushort_t* vp = vt + (size_t)bh * HD * SL;

    short8 qf[2][2];
    #pragma unroll
    for (int mi = 0; mi < 2; ++mi)
        #pragma unroll
        for (int ks = 0; ks < 2; ++ks)
            qf[mi][ks] = *(const short8*)&qp[(size_t)(w * 32 + mi * 16 + c) * HD
                                             + ks * 32 + quad * 8];

    // constant all-ones bf16 B-fragment for the row-sum MFMA
    const short one_bf = (short)0x3F80;
    const short8 ones8 = {one_bf, one_bf, one_bf, one_bf,
                          one_bf, one_bf, one_bf, one_bf};

    // ---- kt-invariant LDS byte offsets (static-indexed) ----
    int kfo[4][2], vfo[4][2], pfo[2][2], pwo[2][4];
    #pragma unroll
    for (int ni = 0; ni < 4; ++ni)
        #pragma unroll
        for (int ks = 0; ks < 2; ++ks) {
            kfo[ni][ks] = (4 * c + ni) * 64 + (((ks * 4 + quad) ^ (c & 7)) << 3);
            vfo[ni][ks] = (ni * 16 + c) * 64 + (((ks * 4 + quad) ^ (c & 7)) << 3);
        }
    #pragma unroll
    for (int mi = 0; mi < 2; ++mi) {
        #pragma unroll
        for (int ks = 0; ks < 2; ++ks) {
            const int prow = w * 32 + mi * 16 + c;
            pfo[mi][ks] = prow * 64 + (((ks * 4 + quad) ^ (prow & 7)) << 3);
        }
        #pragma unroll
        for (int reg = 0; reg < 4; ++reg) {
            const int prow = w * 32 + mi * 16 + quad * 4 + reg;
            pwo[mi][reg] = prow * 64 + (((c >> 1) ^ (prow & 7)) * 8)
                           + ((c & 1) * 4);
        }
    }

    // ---- strength-reduced staging pointers (advance per kt) ----
    // K swizzle keyed (r>>2)&7 (QK^T reads row 4c+ni); V keyed r&7 (PV row ni*16+c)
    const ushort_t* kst[2]; const ushort_t* vst[2];
    #pragma unroll
    for (int rd = 0; rd < 2; ++rd) {
        const int t = (rd * 4 + w) * 64 + lane;
        const int r = t >> 3, sc = t & 7;
        kst[rd] = kp + (size_t)r * HD + (sc ^ ((r >> 2) & 7)) * 8;
        vst[rd] = vp + (size_t)r * SL + (sc ^ (r & 7)) * 8;
    }
    const int* mp = mask + b * SL + 4 * c;

    f32x4 oa[2][4];
    f32x4 oa1[2];                      // row-sum accumulators (replace l_s)
    const f32x4 zero = {0.f, 0.f, 0.f, 0.f};
    #pragma unroll
    for (int mi = 0; mi < 2; ++mi) {
        oa1[mi] = zero;
        #pragma unroll
        for (int ni = 0; ni < 4; ++ni) oa[mi][ni] = zero;
    }

    for (int kt = 0; kt < SL / 64; ++kt) {
        __syncthreads();
        load_lds16(kst[0], Ks + (0 * 4 + w) * 512);
        load_lds16(vst[0], Vs + (0 * 4 + w) * 512);
        load_lds16(kst[1], Ks + (1 * 4 + w) * 512);
        load_lds16(vst[1], Vs + (1 * 4 + w) * 512);
        kst[0] += 64 * HD; kst[1] += 64 * HD;
        vst[0] += 64;      vst[1] += 64;
        __syncthreads();

        // mask -> additive log2-domain bias, folded into the MFMA C-init
        const int4 mzv = *(const int4*)mp;
        mp += 64;
        float mb[4];
        mb[0] = (mzv.x == 0) ? -20000.f : 0.f;
        mb[1] = (mzv.y == 0) ? -20000.f : 0.f;
        mb[2] = (mzv.z == 0) ? -20000.f : 0.f;
        mb[3] = (mzv.w == 0) ? -20000.f : 0.f;

        // S = Q @ K^T + mask_bias, log2 domain. Col c of tile ni = key 4c+ni.
        f32x4 sf[2][4];
        #pragma unroll
        for (int mi = 0; mi < 2; ++mi)
            #pragma unroll
            for (int ni = 0; ni < 4; ++ni) {
                const f32x4 init = {mb[ni], mb[ni], mb[ni], mb[ni]};
                sf[mi][ni] = init;
            }
        __builtin_amdgcn_s_setprio(1);
        #pragma unroll
        for (int ni = 0; ni < 4; ++ni) {
            #pragma unroll
            for (int ks = 0; ks < 2; ++ks) {
                const short8 kf = *(const short8*)&Ks[kfo[ni][ks]];
                #pragma unroll
                for (int mi = 0; mi < 2; ++mi)
                    sf[mi][ni] = __builtin_amdgcn_mfma_f32_16x16x32_bf16(
                        qf[mi][ks], kf, sf[mi][ni], 0, 0, 0);
            }
        }
        __builtin_amdgcn_s_setprio(0);

        #pragma unroll
        for (int mi = 0; mi < 2; ++mi) {
            #pragma unroll
            for (int reg = 0; reg < 4; ++reg) {
                float p[4];
                #pragma unroll
                for (int ni = 0; ni < 4; ++ni)
                    p[ni] = __builtin_amdgcn_exp2f(sf[mi][ni][reg]);
                union { float f; uint_t u; } u0, u1, u2, u3;
                u0.f = p[0]; u1.f = p[1]; u2.f = p[2]; u3.f = p[3];
                uint2 pk;
                pk.x = __builtin_amdgcn_perm(u1.u, u0.u, 0x07060302u);
                pk.y = __builtin_amdgcn_perm(u3.u, u2.u, 0x07060302u);
                *(uint2*)&Ps[pwo[mi][reg]] = pk;
            }
        }
        // wave-local LDS round-trip: no barrier needed

        short8 pf[2][2];
        #pragma unroll
        for (int mi = 0; mi < 2; ++mi)
            #pragma unroll
            for (int ks = 0; ks < 2; ++ks)
                pf[mi][ks] = *(const short8*)&Ps[pfo[mi][ks]];
        __builtin_amdgcn_s_setprio(1);
        #pragma unroll
        for (int ni = 0; ni < 4; ++ni) {
            #pragma unroll
            for (int ks = 0; ks < 2; ++ks) {
                const short8 vf = *(const short8*)&Vs[vfo[ni][ks]];
                #pragma unroll
                for (int mi = 0; mi < 2; ++mi)
                    oa[mi][ni] = __builtin_amdgcn_mfma_f32_16x16x32_bf16(
                        pf[mi][ks], vf, oa[mi][ni], 0, 0, 0);
            }
        }
        // row-sum: l += P @ ones (constant B fragment, no LDS read)
        #pragma unroll
        for (int mi = 0; mi < 2; ++mi)
            #pragma unroll
            for (int ks = 0; ks < 2; ++ks)
                oa1[mi] = __builtin_amdgcn_mfma_f32_16x16x32_bf16(
                    pf[mi][ks], ones8, oa1[mi], 0, 0, 0);
        __builtin_amdgcn_s_setprio(0);
    }

    #pragma unroll
    for (int mi = 0; mi < 2; ++mi) {
        #pragma unroll
        for (int reg = 0; reg < 4; ++reg) {
            const float inv = 1.f / oa1[mi][reg];   // full row sum, every lane
            const int s_g = qt * 128 + w * 32 + mi * 16 + quad * 4 + reg;
            #pragma unroll
            for (int ni = 0; ni < 4; ++ni) {
                const int d = ni * 16 + c;
                ao[((size_t)(b * SL + s_g)) * HID + h * HD + d] =
                    (ushort_t)f2bf(oa[mi][ni][reg] * inv);
            }
        }
    }
}

// ---------------------------------------------------------------------------
// Output projection: out(fp32) = ao_bf @ Wo^T + bo.
//
// v12: 64x128 tiles, grid (8,128) = 1024 blocks = 4 blocks/CU.  The old
// (8,64) = 512-block version ran at only 2 blocks/CU (8 waves) -- the
// 2-barrier drain structure with almost no cross-block TLP, same starvation
// mechanism measured on attn.  LDS = As 8 KB + Bs 16 KB = 24 KB (cap 6);
// acc 2x4 (32 regs) + ~50 arch under the (256,4) 128-reg cap -- no spill.
// Staging/MFMA ratio worsens (375 vs 256 B/MFMA) but 2->4 blocks from a
// STARVED baseline should dominate (unlike R6's 4->8 attn regression).
// XCD banding: XCD j owns 16 m-tiles (rows [j*1024,(j+1)*1024)) x all 8
// n-tiles; A-band 2 MB + Wo 2 MB = 4 MB = L2.  Bijective.
// ---------------------------------------------------------------------------
__global__ __launch_bounds__(256, 4) void out_mfma_kernel(
    const ushort_t* __restrict__ aob, const ushort_t* __restrict__ wob,
    const float* __restrict__ bo, float* __restrict__ out)
{
    __shared__ __align__(16) ushort_t As[64 * 64];    // 8 KB
    __shared__ __align__(16) ushort_t Bs[128 * 64];   // 16 KB

    const int flat = blockIdx.x + (blockIdx.y << 3);   // 0..1023
    const int xcd = flat & 7, s = flat >> 3;           // s: 0..127
    const int m0 = ((xcd << 4) + (s >> 3)) * 64;       // m-tile 0..127
    const int n0 = (s & 7) * 128;

    const int tid = threadIdx.x;
    const int w = tid >> 6, lane = tid & 63;
    const int wm = (w & 1) << 5;        // 0 / 32
    const int wn = (w >> 1) << 6;       // 0 / 64
    const int c = lane & 15, quad = lane >> 4;

    f32x4 acc[2][4];
    const f32x4 zero = {0.f, 0.f, 0.f, 0.f};
    #pragma unroll
    for (int i = 0; i < 2; ++i)
        #pragma unroll
        for (int j = 0; j < 4; ++j) acc[i][j] = zero;

    for (int k0 = 0; k0 < HID; k0 += 64) {
        __syncthreads();
        // A: 64 rows = 512 chunks = 2/thread (groups 0..7)
        #pragma unroll
        for (int rd = 0; rd < 2; ++rd) {
            const int g = rd * 4 + w;            // 0..7
            const int idx = g * 64 + lane;       // 0..511
            const int r = idx >> 3, sc = idx & 7;
            const int dc = sc ^ (r & 7);
            load_lds16(&aob[(size_t)(m0 + r) * HID + k0 + dc * 8], As + g * 512);
        }
        // B: 128 rows = 1024 chunks = 4/thread (groups 0..15)
        #pragma unroll
        for (int rd = 0; rd < 4; ++rd) {
            const int g = rd * 4 + w;            // 0..15
            const int idx = g * 64 + lane;       // 0..1023
            const int r = idx >> 3, sc = idx & 7;
            const int dc = sc ^ (r & 7);
            load_lds16(&wob[(size_t)(n0 + r) * HID + k0 + dc * 8], Bs + g * 512);
        }
        __syncthreads();

        #pragma unroll
        for (int ks = 0; ks < 2; ++ks) {
            short8 af[2], bf[4];
            #pragma unroll
            for (int i = 0; i < 2; ++i) {
                const int ra = wm + i * 16 + c;
                af[i] = *(const short8*)
                    &As[ra * 64 + ((((ks << 2) + quad) ^ (c & 7)) << 3)];
            }
            #pragma unroll
            for (int j = 0; j < 4; ++j) {
                const int rb = wn + j * 16 + c;
                bf[j] = *(const short8*)
                    &Bs[rb * 64 + ((((ks << 2) + quad) ^ (c & 7)) << 3)];
            }
            #pragma unroll
            for (int i = 0; i < 2; ++i)
                #pragma unroll
                for (int j = 0; j < 4; ++j)
                    acc[i][j] = __builtin_amdgcn_mfma_f32_16x16x32_bf16(
                        af[i], bf[j], acc[i][j], 0, 0, 0);
        }
    }

    #pragma unroll
    for (int j = 0; j < 4; ++j) {
        const int n_g = n0 + wn + j * 16 + c;
        const float bj = bo[n_g];
        #pragma unroll
        for (int i = 0; i < 2; ++i) {
            const int mbase = m0 + wm + i * 16 + quad * 4;
            #pragma unroll
            for (int reg = 0; reg < 4; ++reg)
                out[(size_t)(mbase + reg) * HID + n_g] = acc[i][j][reg] + bj;
        }
    }
}

extern "C" void kernel_launch(void* const* d_in, const int* in_sizes, int n_in,
                              void* d_out, int out_size, void* d_ws, size_t ws_size,
                              hipStream_t stream)
{
    const float* x    = (const float*)d_in[0];
    const int*   mask = (const int*)d_in[1];
    const float* Wq   = (const float*)d_in[2];
    const float* bq   = (const float*)d_in[3];
    const float* Wk   = (const float*)d_in[4];
    const float* bk   = (const float*)d_in[5];
    const float* Wv   = (const float*)d_in[6];
    const float* bv   = (const float*)d_in[7];
    const float* Wo   = (const float*)d_in[8];
    const float* bo   = (const float*)d_in[9];
    float* out = (float*)d_out;

    ushort_t* p = (ushort_t*)d_ws;
    ushort_t* xb  = p; p += (size_t)MROWS * HID;
    ushort_t* wqb = p; p += (size_t)HID * HID;
    ushort_t* wkb = p; p += (size_t)HID * HID;
    ushort_t* wvb = p; p += (size_t)HID * HID;
    ushort_t* wob = p; p += (size_t)HID * HID;
    ushort_t* qb  = p; p += (size_t)MROWS * HID;
    ushort_t* kb  = p; p += (size_t)MROWS * HID;
    ushort_t* vtb = p; p += (size_t)MROWS * HID;
    ushort_t* aob = p; p += (size_t)MROWS * HID;

    cvt_bf16_kernel<<<dim3(512, 12), 256, 0, stream>>>(
        x, Wq, Wk, Wv, Wo, xb, wqb, wkb, wvb, wob);
    qkv_mfma_kernel<<<dim3(8, 64, 3), 256, 0, stream>>>(
        xb, wqb, wkb, wvb, bq, bk, bv, qb, kb, vtb);
    attn_mfma_kernel<<<dim3(16, 64), 256, 0, stream>>>(
        qb, kb, vtb, mask, aob);
    out_mfma_kernel<<<dim3(8, 128), 256, 0, stream>>>(
        aob, wob, bo, out);
}

// Round 13
// 280.402 us; speedup vs baseline: 1.0206x; 1.0206x over previous
//
#include <hip/hip_runtime.h>
#include <math.h>

#define HID 1024
#define NH  16
#define HD  64
#define NB  4
#define SL  2048
#define MROWS (NB * SL)   // 8192

typedef __attribute__((ext_vector_type(8))) short short8;
typedef __attribute__((ext_vector_type(4))) float f32x4;
typedef unsigned short ushort_t;
typedef unsigned int uint_t;

// fp32 -> bf16 bits, round-to-nearest-even
__device__ __forceinline__ uint_t f2bf(float x) {
    union { float f; uint_t u; } a; a.f = x;
    return (a.u + 0x7fffu + ((a.u >> 16) & 1u)) >> 16;
}

// async global->LDS, 16B per lane; LDS dest = wave-uniform base + lane*16
__device__ __forceinline__ void load_lds16(const void* g, void* l) {
    __builtin_amdgcn_global_load_lds(
        (const __attribute__((address_space(1))) void*)g,
        (__attribute__((address_space(3))) void*)l, 16, 0, 0);
}

// ---------------------------------------------------------------------------
// GEMM core: C(128x128) = A @ B^T, bf16, BK=64 (16 k-iters, 32 MFMA/wave/iter).
// LDS rows are 128 B = exactly 32 banks (row drops out of bank equation);
// chunks XOR-swizzled with r&7 (== c&7 at read) -> fragment b128 reads spread
// evenly over the 8 bank-groups.
// ---------------------------------------------------------------------------
__device__ __forceinline__ void gemm_core_bk64(
    const ushort_t* __restrict__ A, const ushort_t* __restrict__ B,
    const int m0, const int n0, ushort_t* As, ushort_t* Bs, f32x4 (&acc)[4][4])
{
    const int tid = threadIdx.x;
    const int w = tid >> 6, lane = tid & 63;
    const int wm = (w & 1) << 6, wn = (w >> 1) << 6;
    const int c = lane & 15, quad = lane >> 4;

    for (int k0 = 0; k0 < HID; k0 += 64) {
        __syncthreads();
        #pragma unroll
        for (int rd = 0; rd < 4; ++rd) {
            const int g = rd * 4 + w;            // wave-uniform group 0..15
            const int idx = g * 64 + lane;       // 16B-chunk id, 0..1023
            const int r = idx >> 3, sc = idx & 7;
            const int dc = sc ^ (r & 7);         // fetch permuted chunk
            load_lds16(&A[(size_t)(m0 + r) * HID + k0 + dc * 8], As + g * 512);
            load_lds16(&B[(size_t)(n0 + r) * HID + k0 + dc * 8], Bs + g * 512);
        }
        __syncthreads();

        #pragma unroll
        for (int ks = 0; ks < 2; ++ks) {
            short8 af[4], bf[4];
            #pragma unroll
            for (int i = 0; i < 4; ++i) {
                const int ra = wm + i * 16 + c;
                const int rb = wn + i * 16 + c;
                af[i] = *(const short8*)
                    &As[ra * 64 + ((((ks << 2) + quad) ^ (c & 7)) << 3)];
                bf[i] = *(const short8*)
                    &Bs[rb * 64 + ((((ks << 2) + quad) ^ (c & 7)) << 3)];
            }
            #pragma unroll
            for (int i = 0; i < 4; ++i)
                #pragma unroll
                for (int j = 0; j < 4; ++j)
                    acc[i][j] = __builtin_amdgcn_mfma_f32_16x16x32_bf16(
                        af[i], bf[j], acc[i][j], 0, 0, 0);
        }
    }
}

// ---------------------------------------------------------------------------
// fp32 -> bf16 conversion: 12 segments of 1M elems (x = 8 segs, 4 weights)
// ---------------------------------------------------------------------------
__global__ __launch_bounds__(256) void cvt_bf16_kernel(
    const float* __restrict__ x,
    const float* __restrict__ wq, const float* __restrict__ wk,
    const float* __restrict__ wv, const float* __restrict__ wo,
    ushort_t* __restrict__ xb, ushort_t* __restrict__ wqb,
    ushort_t* __restrict__ wkb, ushort_t* __restrict__ wvb,
    ushort_t* __restrict__ wob)
{
    const int seg = blockIdx.y;
    const float* src; ushort_t* dst;
    if (seg < 8)       { src = x + (size_t)seg * 1048576; dst = xb + (size_t)seg * 1048576; }
    else if (seg == 8) { src = wq; dst = wqb; }
    else if (seg == 9) { src = wk; dst = wkb; }
    else if (seg == 10){ src = wv; dst = wvb; }
    else               { src = wo; dst = wob; }
    const int i = (blockIdx.x * 256 + threadIdx.x) * 8;
    const float4 a = *(const float4*)&src[i];
    const float4 b = *(const float4*)&src[i + 4];
    uint4 o;
    o.x = f2bf(a.x) | (f2bf(a.y) << 16);
    o.y = f2bf(a.z) | (f2bf(a.w) << 16);
    o.z = f2bf(b.x) | (f2bf(b.y) << 16);
    o.w = f2bf(b.z) | (f2bf(b.w) << 16);
    *(uint4*)&dst[i] = o;
}

// ---------------------------------------------------------------------------
// QKV projection. grid (8 n-tiles, 64 m-tiles, 3 weights); 128x128 tile.
// Q pre-scaled by 0.125*log2(e); K as (B,H,S,D); V^T as (B,H,D,S).
//
// XCD-banded block remap (kept -- R7 isolated the pipeline gain to this):
// flat=x+8y, xcd=flat&7, s=flat>>3 -> (ny = xcd*8 + s/8, nx = s%8): XCD j
// owns m-band [8j,8j+8) x all 8 n-tiles.  Per-XCD L2 working set = weight
// 2 MB + A-band 2 MB = 4 MB = L2; A reused 8x in-XCD.
// ---------------------------------------------------------------------------
__global__ __launch_bounds__(256) void qkv_mfma_kernel(
    const ushort_t* __restrict__ xb,
    const ushort_t* __restrict__ wqb, const ushort_t* __restrict__ wkb,
    const ushort_t* __restrict__ wvb,
    const float* __restrict__ bq, const float* __restrict__ bk,
    const float* __restrict__ bv,
    ushort_t* __restrict__ qo, ushort_t* __restrict__ ko,
    ushort_t* __restrict__ vo)
{
    __shared__ __align__(16) ushort_t As[128 * 64];   // 16 KB
    __shared__ __align__(16) ushort_t Bs[128 * 64];   // 16 KB

    const int wsel = blockIdx.z;
    const ushort_t* W    = (wsel == 0) ? wqb : (wsel == 1) ? wkb : wvb;
    const float*    bias = (wsel == 0) ? bq  : (wsel == 1) ? bk  : bv;

    const int flat = blockIdx.x + (blockIdx.y << 3);   // 0..511
    const int xcd = flat & 7, s = flat >> 3;
    const int m0 = ((xcd << 3) + (s >> 3)) * 128;
    const int n0 = (s & 7) * 128;

    f32x4 acc[4][4];
    const f32x4 zero = {0.f, 0.f, 0.f, 0.f};
    #pragma unroll
    for (int i = 0; i < 4; ++i)
        #pragma unroll
        for (int j = 0; j < 4; ++j) acc[i][j] = zero;

    gemm_core_bk64(xb, W, m0, n0, As, Bs, acc);

    const int tid = threadIdx.x;
    const int w = tid >> 6, lane = tid & 63;
    const int wm = (w & 1) << 6, wn = (w >> 1) << 6;
    const int c = lane & 15, quad = lane >> 4;
    // 0.125 (1/sqrt(64)) * log2(e): scores land in log2 domain
    const float qscale = (wsel == 0) ? 0.18033688f : 1.0f;

    #pragma unroll
    for (int j = 0; j < 4; ++j) {
        const int n_g = n0 + wn + j * 16 + c;
        const float bj = bias[n_g];
        const int h = n_g >> 6, d = n_g & 63;
        #pragma unroll
        for (int i = 0; i < 4; ++i) {
            const int mbase = m0 + wm + i * 16 + quad * 4;
            const int b = mbase >> 11;
            const int sbase = mbase & (SL - 1);
            if (wsel == 2) {
                ushort4 pk;
                pk.x = (ushort_t)f2bf(acc[i][j][0] + bj);
                pk.y = (ushort_t)f2bf(acc[i][j][1] + bj);
                pk.z = (ushort_t)f2bf(acc[i][j][2] + bj);
                pk.w = (ushort_t)f2bf(acc[i][j][3] + bj);
                *(ushort4*)&vo[(((size_t)(b * NH + h) * HD) + d) * SL + sbase] = pk;
            } else {
                ushort_t* dst = (wsel == 0) ? qo : ko;
                #pragma unroll
                for (int reg = 0; reg < 4; ++reg) {
                    const float v = (acc[i][j][reg] + bj) * qscale;
                    dst[(((size_t)(b * NH + h) * SL) + sbase + reg) * HD + d] =
                        (ushort_t)f2bf(v);
                }
            }
        }
    }
}

// ---------------------------------------------------------------------------
// MFMA flash attention -- R10-verified best (89.9us): setprio + mask-as-
// MFMA-C-init + ones-column row-sum.  UNCHANGED (control).
// ---------------------------------------------------------------------------
__global__ __launch_bounds__(256, 4) void attn_mfma_kernel(
    const ushort_t* __restrict__ q, const ushort_t* __restrict__ k,
    const ushort_t* __restrict__ vt, const int* __restrict__ mask,
    ushort_t* __restrict__ ao)
{
    __shared__ __align__(16) ushort_t Ks[64 * 64];    // 8 KB
    __shared__ __align__(16) ushort_t Vs[64 * 64];    // 8 KB
    __shared__ __align__(16) ushort_t Ps[128 * 64];   // 16 KB (swizzled)

    const int qt = blockIdx.x;    // 0..15
    const int bh = blockIdx.y;
    const int b = bh >> 4, h = bh & 15;
    const int tid = threadIdx.x;
    const int w = tid >> 6, lane = tid & 63;
    const int c = lane & 15, quad = lane >> 4;

    const ushort_t* qp = q  + (size_t)bh * SL * HD + (size_t)qt * 128 * HD;
    const ushort_t* kp = k  + (size_t)bh * SL * HD;
    const ushort_t* vp = vt + (size_t)bh * HD * SL;

    short8 qf[2][2];
    #pragma unroll
    for (int mi = 0; mi < 2; ++mi)
        #pragma unroll
        for (int ks = 0; ks < 2; ++ks)
            qf[mi][ks] = *(const short8*)&qp[(size_t)(w * 32 + mi * 16 + c) * HD
                                             + ks * 32 + quad * 8];

    // constant all-ones bf16 B-fragment for the row-sum MFMA
    const short one_bf = (short)0x3F80;
    const short8 ones8 = {one_bf, one_bf, one_bf, one_bf,
                          one_bf, one_bf, one_bf, one_bf};

    // ---- kt-invariant LDS byte offsets (static-indexed) ----
    int kfo[4][2], vfo[4][2], pfo[2][2], pwo[2][4];
    #pragma unroll
    for (int ni = 0; ni < 4; ++ni)
        #pragma unroll
        for (int ks = 0; ks < 2; ++ks) {
            kfo[ni][ks] = (4 * c + ni) * 64 + (((ks * 4 + quad) ^ (c & 7)) << 3);
            vfo[ni][ks] = (ni * 16 + c) * 64 + (((ks * 4 + quad) ^ (c & 7)) << 3);
        }
    #pragma unroll
    for (int mi = 0; mi < 2; ++mi) {
        #pragma unroll
        for (int ks = 0; ks < 2; ++ks) {
            const int prow = w * 32 + mi * 16 + c;
            pfo[mi][ks] = prow * 64 + (((ks * 4 + quad) ^ (prow & 7)) << 3);
        }
        #pragma unroll
        for (int reg = 0; reg < 4; ++reg) {
            const int prow = w * 32 + mi * 16 + quad * 4 + reg;
            pwo[mi][reg] = prow * 64 + (((c >> 1) ^ (prow & 7)) * 8)
                           + ((c & 1) * 4);
        }
    }

    // ---- strength-reduced staging pointers (advance per kt) ----
    // K swizzle keyed (r>>2)&7 (QK^T reads row 4c+ni); V keyed r&7 (PV row ni*16+c)
    const ushort_t* kst[2]; const ushort_t* vst[2];
    #pragma unroll
    for (int rd = 0; rd < 2; ++rd) {
        const int t = (rd * 4 + w) * 64 + lane;
        const int r = t >> 3, sc = t & 7;
        kst[rd] = kp + (size_t)r * HD + (sc ^ ((r >> 2) & 7)) * 8;
        vst[rd] = vp + (size_t)r * SL + (sc ^ (r & 7)) * 8;
    }
    const int* mp = mask + b * SL + 4 * c;

    f32x4 oa[2][4];
    f32x4 oa1[2];                      // row-sum accumulators (replace l_s)
    const f32x4 zero = {0.f, 0.f, 0.f, 0.f};
    #pragma unroll
    for (int mi = 0; mi < 2; ++mi) {
        oa1[mi] = zero;
        #pragma unroll
        for (int ni = 0; ni < 4; ++ni) oa[mi][ni] = zero;
    }

    for (int kt = 0; kt < SL / 64; ++kt) {
        __syncthreads();
        load_lds16(kst[0], Ks + (0 * 4 + w) * 512);
        load_lds16(vst[0], Vs + (0 * 4 + w) * 512);
        load_lds16(kst[1], Ks + (1 * 4 + w) * 512);
        load_lds16(vst[1], Vs + (1 * 4 + w) * 512);
        kst[0] += 64 * HD; kst[1] += 64 * HD;
        vst[0] += 64;      vst[1] += 64;
        __syncthreads();

        // mask -> additive log2-domain bias, folded into the MFMA C-init
        const int4 mzv = *(const int4*)mp;
        mp += 64;
        float mb[4];
        mb[0] = (mzv.x == 0) ? -20000.f : 0.f;
        mb[1] = (mzv.y == 0) ? -20000.f : 0.f;
        mb[2] = (mzv.z == 0) ? -20000.f : 0.f;
        mb[3] = (mzv.w == 0) ? -20000.f : 0.f;

        // S = Q @ K^T + mask_bias, log2 domain. Col c of tile ni = key 4c+ni.
        f32x4 sf[2][4];
        #pragma unroll
        for (int mi = 0; mi < 2; ++mi)
            #pragma unroll
            for (int ni = 0; ni < 4; ++ni) {
                const f32x4 init = {mb[ni], mb[ni], mb[ni], mb[ni]};
                sf[mi][ni] = init;
            }
        __builtin_amdgcn_s_setprio(1);
        #pragma unroll
        for (int ni = 0; ni < 4; ++ni) {
            #pragma unroll
            for (int ks = 0; ks < 2; ++ks) {
                const short8 kf = *(const short8*)&Ks[kfo[ni][ks]];
                #pragma unroll
                for (int mi = 0; mi < 2; ++mi)
                    sf[mi][ni] = __builtin_amdgcn_mfma_f32_16x16x32_bf16(
                        qf[mi][ks], kf, sf[mi][ni], 0, 0, 0);
            }
        }
        __builtin_amdgcn_s_setprio(0);

        #pragma unroll
        for (int mi = 0; mi < 2; ++mi) {
            #pragma unroll
            for (int reg = 0; reg < 4; ++reg) {
                float p[4];
                #pragma unroll
                for (int ni = 0; ni < 4; ++ni)
                    p[ni] = __builtin_amdgcn_exp2f(sf[mi][ni][reg]);
                union { float f; uint_t u; } u0, u1, u2, u3;
                u0.f = p[0]; u1.f = p[1]; u2.f = p[2]; u3.f = p[3];
                uint2 pk;
                pk.x = __builtin_amdgcn_perm(u1.u, u0.u, 0x07060302u);
                pk.y = __builtin_amdgcn_perm(u3.u, u2.u, 0x07060302u);
                *(uint2*)&Ps[pwo[mi][reg]] = pk;
            }
        }
        // wave-local LDS round-trip: no barrier needed

        short8 pf[2][2];
        #pragma unroll
        for (int mi = 0; mi < 2; ++mi)
            #pragma unroll
            for (int ks = 0; ks < 2; ++ks)
                pf[mi][ks] = *(const short8*)&Ps[pfo[mi][ks]];
        __builtin_amdgcn_s_setprio(1);
        #pragma unroll
        for (int ni = 0; ni < 4; ++ni) {
            #pragma unroll
            for (int ks = 0; ks < 2; ++ks) {
                const short8 vf = *(const short8*)&Vs[vfo[ni][ks]];
                #pragma unroll
                for (int mi = 0; mi < 2; ++mi)
                    oa[mi][ni] = __builtin_amdgcn_mfma_f32_16x16x32_bf16(
                        pf[mi][ks], vf, oa[mi][ni], 0, 0, 0);
            }
        }
        // row-sum: l += P @ ones (constant B fragment, no LDS read)
        #pragma unroll
        for (int mi = 0; mi < 2; ++mi)
            #pragma unroll
            for (int ks = 0; ks < 2; ++ks)
                oa1[mi] = __builtin_amdgcn_mfma_f32_16x16x32_bf16(
                    pf[mi][ks], ones8, oa1[mi], 0, 0, 0);
        __builtin_amdgcn_s_setprio(0);
    }

    #pragma unroll
    for (int mi = 0; mi < 2; ++mi) {
        #pragma unroll
        for (int reg = 0; reg < 4; ++reg) {
            const float inv = 1.f / oa1[mi][reg];   // full row sum, every lane
            const int s_g = qt * 128 + w * 32 + mi * 16 + quad * 4 + reg;
            #pragma unroll
            for (int ni = 0; ni < 4; ++ni) {
                const int d = ni * 16 + c;
                ao[((size_t)(b * SL + s_g)) * HID + h * HD + d] =
                    (ushort_t)f2bf(oa[mi][ni][reg] * inv);
            }
        }
    }
}

// ---------------------------------------------------------------------------
// Output projection: out(fp32) = ao_bf @ Wo^T + bo. grid (8, 64) = 512 blocks
// = exactly 2 blocks/CU (grid-limited).
//
// v13 (resubmit -- R12 was an infra failure, no data): 2-phase double-
// buffered staging, applied where it is FREE.  At 2 blocks/CU: LDS dbuf =
// exactly 64 KB still permits 2 blocks/CU (zero occupancy cost -- v5's
// failure mode excluded), and the per-wave register budget is 256
// (launch_bounds(256,2) pins it; live ~130-150 fits trivially -- v2-v4/v9's
// spill mode excluded; the 64KB LDS already forces the backend's occupancy
// target to 2 waves/SIMD, so no R3-style implicit reg-throttle).  One
// barrier per k-step (16 vs 32); each drain covers loads issued a full
// compute phase (~400 cyc) earlier.  XCD banding unchanged.
// ---------------------------------------------------------------------------
__global__ __launch_bounds__(256, 2) void out_mfma_kernel(
    const ushort_t* __restrict__ aob, const ushort_t* __restrict__ wob,
    const float* __restrict__ bo, float* __restrict__ out)
{
    __shared__ __align__(16) ushort_t As[2][128 * 64];   // 32 KB
    __shared__ __align__(16) ushort_t Bs[2][128 * 64];   // 32 KB

    const int flat = blockIdx.x + (blockIdx.y << 3);   // 0..511
    const int xcd = flat & 7, s = flat >> 3;
    const int m0 = ((xcd << 3) + (s >> 3)) * 128;
    const int n0 = (s & 7) * 128;

    const int tid = threadIdx.x;
    const int w = tid >> 6, lane = tid & 63;
    const int wm = (w & 1) << 6, wn = (w >> 1) << 6;
    const int c = lane & 15, quad = lane >> 4;

    // prologue: stage k=0 into buffer 0
    #pragma unroll
    for (int rd = 0; rd < 4; ++rd) {
        const int g = rd * 4 + w;
        const int idx = g * 64 + lane;
        const int r = idx >> 3, sc = idx & 7;
        const int dc = sc ^ (r & 7);
        load_lds16(&aob[(size_t)(m0 + r) * HID + dc * 8], As[0] + g * 512);
        load_lds16(&wob[(size_t)(n0 + r) * HID + dc * 8], Bs[0] + g * 512);
    }

    f32x4 acc[4][4];
    const f32x4 zero = {0.f, 0.f, 0.f, 0.f};
    #pragma unroll
    for (int i = 0; i < 4; ++i)
        #pragma unroll
        for (int j = 0; j < 4; ++j) acc[i][j] = zero;

    for (int k0 = 0; k0 < HID; k0 += 128) {
        #pragma unroll
        for (int half = 0; half < 2; ++half) {
            const int kk = k0 + half * 64;      // runtime base, static parity
            const int cur = half, nxt = half ^ 1;

            // drains tile-kk loads (issued a full compute phase ago) and
            // guarantees all waves finished reading buf[nxt] (step kk-64)
            __syncthreads();

            // issue next k-step's loads; they fly through this compute phase
            if (kk + 64 < HID) {
                #pragma unroll
                for (int rd = 0; rd < 4; ++rd) {
                    const int g = rd * 4 + w;
                    const int idx = g * 64 + lane;
                    const int r = idx >> 3, sc = idx & 7;
                    const int dc = sc ^ (r & 7);
                    load_lds16(&aob[(size_t)(m0 + r) * HID + kk + 64 + dc * 8],
                               As[nxt] + g * 512);
                    load_lds16(&wob[(size_t)(n0 + r) * HID + kk + 64 + dc * 8],
                               Bs[nxt] + g * 512);
                }
            }

            #pragma unroll
            for (int ks = 0; ks < 2; ++ks) {
                short8 af[4], bf[4];
                #pragma unroll
                for (int i = 0; i < 4; ++i) {
                    const int ra = wm + i * 16 + c;
                    const int rb = wn + i * 16 + c;
                    af[i] = *(const short8*)
                        &As[cur][ra * 64 + ((((ks << 2) + quad) ^ (c & 7)) << 3)];
                    bf[i] = *(const short8*)
                        &Bs[cur][rb * 64 + ((((ks << 2) + quad) ^ (c & 7)) << 3)];
                }
                #pragma unroll
                for (int i = 0; i < 4; ++i)
                    #pragma unroll
                    for (int j = 0; j < 4; ++j)
                        acc[i][j] = __builtin_amdgcn_mfma_f32_16x16x32_bf16(
                            af[i], bf[j], acc[i][j], 0, 0, 0);
            }
        }
    }

    #pragma unroll
    for (int j = 0; j < 4; ++j) {
        const int n_g = n0 + wn + j * 16 + c;
        const float bj = bo[n_g];
        #pragma unroll
        for (int i = 0; i < 4; ++i) {
            const int mbase = m0 + wm + i * 16 + quad * 4;
            #pragma unroll
            for (int reg = 0; reg < 4; ++reg)
                out[(size_t)(mbase + reg) * HID + n_g] = acc[i][j][reg] + bj;
        }
    }
}

extern "C" void kernel_launch(void* const* d_in, const int* in_sizes, int n_in,
                              void* d_out, int out_size, void* d_ws, size_t ws_size,
                              hipStream_t stream)
{
    const float* x    = (const float*)d_in[0];
    const int*   mask = (const int*)d_in[1];
    const float* Wq   = (const float*)d_in[2];
    const float* bq   = (const float*)d_in[3];
    const float* Wk   = (const float*)d_in[4];
    const float* bk   = (const float*)d_in[5];
    const float* Wv   = (const float*)d_in[6];
    const float* bv   = (const float*)d_in[7];
    const float* Wo   = (const float*)d_in[8];
    const float* bo   = (const float*)d_in[9];
    float* out = (float*)d_out;

    ushort_t* p = (ushort_t*)d_ws;
    ushort_t* xb  = p; p += (size_t)MROWS * HID;
    ushort_t* wqb = p; p += (size_t)HID * HID;
    ushort_t* wkb = p; p += (size_t)HID * HID;
    ushort_t* wvb = p; p += (size_t)HID * HID;
    ushort_t* wob = p; p += (size_t)HID * HID;
    ushort_t* qb  = p; p += (size_t)MROWS * HID;
    ushort_t* kb  = p; p += (size_t)MROWS * HID;
    ushort_t* vtb = p; p += (size_t)MROWS * HID;
    ushort_t* aob = p; p += (size_t)MROWS * HID;

    cvt_bf16_kernel<<<dim3(512, 12), 256, 0, stream>>>(
        x, Wq, Wk, Wv, Wo, xb, wqb, wkb, wvb, wob);
    qkv_mfma_kernel<<<dim3(8, 64, 3), 256, 0, stream>>>(
        xb, wqb, wkb, wvb, bq, bk, bv, qb, kb, vtb);
    attn_mfma_kernel<<<dim3(16, 64), 256, 0, stream>>>(
        qb, kb, vtb, mask, aob);
    out_mfma_kernel<<<dim3(8, 64), 256, 0, stream>>>(
        aob, wob, bo, out);
}

// Round 14
// 264.082 us; speedup vs baseline: 1.0836x; 1.0618x over previous
//
#include <hip/hip_runtime.h>
#include <math.h>

#define HID 1024
#define NH  16
#define HD  64
#define NB  4
#define SL  2048
#define MROWS (NB * SL)   // 8192

typedef __attribute__((ext_vector_type(8))) short short8;
typedef __attribute__((ext_vector_type(4))) float f32x4;
typedef unsigned short ushort_t;
typedef unsigned int uint_t;

// fp32 -> bf16 bits, round-to-nearest-even
__device__ __forceinline__ uint_t f2bf(float x) {
    union { float f; uint_t u; } a; a.f = x;
    return (a.u + 0x7fffu + ((a.u >> 16) & 1u)) >> 16;
}

// async global->LDS, 16B per lane; LDS dest = wave-uniform base + lane*16
__device__ __forceinline__ void load_lds16(const void* g, void* l) {
    __builtin_amdgcn_global_load_lds(
        (const __attribute__((address_space(1))) void*)g,
        (__attribute__((address_space(3))) void*)l, 16, 0, 0);
}

// ---------------------------------------------------------------------------
// GEMM core: C(128x128) = A @ B^T, bf16, BK=64 (16 k-iters, 32 MFMA/wave/iter).
// LDS rows are 128 B = exactly 32 banks (row drops out of bank equation);
// chunks XOR-swizzled with r&7 (== c&7 at read) -> fragment b128 reads spread
// evenly over the 8 bank-groups.
//
// v14: T5 setprio around the MFMA cluster.  m190's GEMM-null was a single-
// block lockstep structure; here qkv runs 4-5 independent blocks/CU and out
// 2/CU -- the R9-measured regime (mixed-phase co-resident blocks) where
// setprio bought attn +5%.  Zero register / LDS / structural cost.
// ---------------------------------------------------------------------------
__device__ __forceinline__ void gemm_core_bk64(
    const ushort_t* __restrict__ A, const ushort_t* __restrict__ B,
    const int m0, const int n0, ushort_t* As, ushort_t* Bs, f32x4 (&acc)[4][4])
{
    const int tid = threadIdx.x;
    const int w = tid >> 6, lane = tid & 63;
    const int wm = (w & 1) << 6, wn = (w >> 1) << 6;
    const int c = lane & 15, quad = lane >> 4;

    for (int k0 = 0; k0 < HID; k0 += 64) {
        __syncthreads();
        #pragma unroll
        for (int rd = 0; rd < 4; ++rd) {
            const int g = rd * 4 + w;            // wave-uniform group 0..15
            const int idx = g * 64 + lane;       // 16B-chunk id, 0..1023
            const int r = idx >> 3, sc = idx & 7;
            const int dc = sc ^ (r & 7);         // fetch permuted chunk
            load_lds16(&A[(size_t)(m0 + r) * HID + k0 + dc * 8], As + g * 512);
            load_lds16(&B[(size_t)(n0 + r) * HID + k0 + dc * 8], Bs + g * 512);
        }
        __syncthreads();

        __builtin_amdgcn_s_setprio(1);
        #pragma unroll
        for (int ks = 0; ks < 2; ++ks) {
            short8 af[4], bf[4];
            #pragma unroll
            for (int i = 0; i < 4; ++i) {
                const int ra = wm + i * 16 + c;
                const int rb = wn + i * 16 + c;
                af[i] = *(const short8*)
                    &As[ra * 64 + ((((ks << 2) + quad) ^ (c & 7)) << 3)];
                bf[i] = *(const short8*)
                    &Bs[rb * 64 + ((((ks << 2) + quad) ^ (c & 7)) << 3)];
            }
            #pragma unroll
            for (int i = 0; i < 4; ++i)
                #pragma unroll
                for (int j = 0; j < 4; ++j)
                    acc[i][j] = __builtin_amdgcn_mfma_f32_16x16x32_bf16(
                        af[i], bf[j], acc[i][j], 0, 0, 0);
        }
        __builtin_amdgcn_s_setprio(0);
    }
}

// ---------------------------------------------------------------------------
// fp32 -> bf16 conversion: 12 segments of 1M elems (x = 8 segs, 4 weights)
// ---------------------------------------------------------------------------
__global__ __launch_bounds__(256) void cvt_bf16_kernel(
    const float* __restrict__ x,
    const float* __restrict__ wq, const float* __restrict__ wk,
    const float* __restrict__ wv, const float* __restrict__ wo,
    ushort_t* __restrict__ xb, ushort_t* __restrict__ wqb,
    ushort_t* __restrict__ wkb, ushort_t* __restrict__ wvb,
    ushort_t* __restrict__ wob)
{
    const int seg = blockIdx.y;
    const float* src; ushort_t* dst;
    if (seg < 8)       { src = x + (size_t)seg * 1048576; dst = xb + (size_t)seg * 1048576; }
    else if (seg == 8) { src = wq; dst = wqb; }
    else if (seg == 9) { src = wk; dst = wkb; }
    else if (seg == 10){ src = wv; dst = wvb; }
    else               { src = wo; dst = wob; }
    const int i = (blockIdx.x * 256 + threadIdx.x) * 8;
    const float4 a = *(const float4*)&src[i];
    const float4 b = *(const float4*)&src[i + 4];
    uint4 o;
    o.x = f2bf(a.x) | (f2bf(a.y) << 16);
    o.y = f2bf(a.z) | (f2bf(a.w) << 16);
    o.z = f2bf(b.x) | (f2bf(b.y) << 16);
    o.w = f2bf(b.z) | (f2bf(b.w) << 16);
    *(uint4*)&dst[i] = o;
}

// ---------------------------------------------------------------------------
// QKV projection. grid (8 n-tiles, 64 m-tiles, 3 weights); 128x128 tile.
// Q pre-scaled by 0.125*log2(e); K as (B,H,S,D); V^T as (B,H,D,S).
//
// XCD-banded block remap (kept -- R7 isolated the pipeline gain to this):
// flat=x+8y, xcd=flat&7, s=flat>>3 -> (ny = xcd*8 + s/8, nx = s%8): XCD j
// owns m-band [8j,8j+8) x all 8 n-tiles.  Per-XCD L2 working set = weight
// 2 MB + A-band 2 MB = 4 MB = L2; A reused 8x in-XCD.
// ---------------------------------------------------------------------------
__global__ __launch_bounds__(256) void qkv_mfma_kernel(
    const ushort_t* __restrict__ xb,
    const ushort_t* __restrict__ wqb, const ushort_t* __restrict__ wkb,
    const ushort_t* __restrict__ wvb,
    const float* __restrict__ bq, const float* __restrict__ bk,
    const float* __restrict__ bv,
    ushort_t* __restrict__ qo, ushort_t* __restrict__ ko,
    ushort_t* __restrict__ vo)
{
    __shared__ __align__(16) ushort_t As[128 * 64];   // 16 KB
    __shared__ __align__(16) ushort_t Bs[128 * 64];   // 16 KB

    const int wsel = blockIdx.z;
    const ushort_t* W    = (wsel == 0) ? wqb : (wsel == 1) ? wkb : wvb;
    const float*    bias = (wsel == 0) ? bq  : (wsel == 1) ? bk  : bv;

    const int flat = blockIdx.x + (blockIdx.y << 3);   // 0..511
    const int xcd = flat & 7, s = flat >> 3;
    const int m0 = ((xcd << 3) + (s >> 3)) * 128;
    const int n0 = (s & 7) * 128;

    f32x4 acc[4][4];
    const f32x4 zero = {0.f, 0.f, 0.f, 0.f};
    #pragma unroll
    for (int i = 0; i < 4; ++i)
        #pragma unroll
        for (int j = 0; j < 4; ++j) acc[i][j] = zero;

    gemm_core_bk64(xb, W, m0, n0, As, Bs, acc);

    const int tid = threadIdx.x;
    const int w = tid >> 6, lane = tid & 63;
    const int wm = (w & 1) << 6, wn = (w >> 1) << 6;
    const int c = lane & 15, quad = lane >> 4;
    // 0.125 (1/sqrt(64)) * log2(e): scores land in log2 domain
    const float qscale = (wsel == 0) ? 0.18033688f : 1.0f;

    #pragma unroll
    for (int j = 0; j < 4; ++j) {
        const int n_g = n0 + wn + j * 16 + c;
        const float bj = bias[n_g];
        const int h = n_g >> 6, d = n_g & 63;
        #pragma unroll
        for (int i = 0; i < 4; ++i) {
            const int mbase = m0 + wm + i * 16 + quad * 4;
            const int b = mbase >> 11;
            const int sbase = mbase & (SL - 1);
            if (wsel == 2) {
                ushort4 pk;
                pk.x = (ushort_t)f2bf(acc[i][j][0] + bj);
                pk.y = (ushort_t)f2bf(acc[i][j][1] + bj);
                pk.z = (ushort_t)f2bf(acc[i][j][2] + bj);
                pk.w = (ushort_t)f2bf(acc[i][j][3] + bj);
                *(ushort4*)&vo[(((size_t)(b * NH + h) * HD) + d) * SL + sbase] = pk;
            } else {
                ushort_t* dst = (wsel == 0) ? qo : ko;
                #pragma unroll
                for (int reg = 0; reg < 4; ++reg) {
                    const float v = (acc[i][j][reg] + bj) * qscale;
                    dst[(((size_t)(b * NH + h) * SL) + sbase + reg) * HD + d] =
                        (ushort_t)f2bf(v);
                }
            }
        }
    }
}

// ---------------------------------------------------------------------------
// MFMA flash attention -- R10-verified best (89-90us): setprio + mask-as-
// MFMA-C-init + ones-column row-sum.  UNCHANGED (control).
// ---------------------------------------------------------------------------
__global__ __launch_bounds__(256, 4) void attn_mfma_kernel(
    const ushort_t* __restrict__ q, const ushort_t* __restrict__ k,
    const ushort_t* __restrict__ vt, const int* __restrict__ mask,
    ushort_t* __restrict__ ao)
{
    __shared__ __align__(16) ushort_t Ks[64 * 64];    // 8 KB
    __shared__ __align__(16) ushort_t Vs[64 * 64];    // 8 KB
    __shared__ __align__(16) ushort_t Ps[128 * 64];   // 16 KB (swizzled)

    const int qt = blockIdx.x;    // 0..15
    const int bh = blockIdx.y;
    const int b = bh >> 4, h = bh & 15;
    const int tid = threadIdx.x;
    const int w = tid >> 6, lane = tid & 63;
    const int c = lane & 15, quad = lane >> 4;

    const ushort_t* qp = q  + (size_t)bh * SL * HD + (size_t)qt * 128 * HD;
    const ushort_t* kp = k  + (size_t)bh * SL * HD;
    const ushort_t* vp = vt + (size_t)bh * HD * SL;

    short8 qf[2][2];
    #pragma unroll
    for (int mi = 0; mi < 2; ++mi)
        #pragma unroll
        for (int ks = 0; ks < 2; ++ks)
            qf[mi][ks] = *(const short8*)&qp[(size_t)(w * 32 + mi * 16 + c) * HD
                                             + ks * 32 + quad * 8];

    // constant all-ones bf16 B-fragment for the row-sum MFMA
    const short one_bf = (short)0x3F80;
    const short8 ones8 = {one_bf, one_bf, one_bf, one_bf,
                          one_bf, one_bf, one_bf, one_bf};

    // ---- kt-invariant LDS byte offsets (static-indexed) ----
    int kfo[4][2], vfo[4][2], pfo[2][2], pwo[2][4];
    #pragma unroll
    for (int ni = 0; ni < 4; ++ni)
        #pragma unroll
        for (int ks = 0; ks < 2; ++ks) {
            kfo[ni][ks] = (4 * c + ni) * 64 + (((ks * 4 + quad) ^ (c & 7)) << 3);
            vfo[ni][ks] = (ni * 16 + c) * 64 + (((ks * 4 + quad) ^ (c & 7)) << 3);
        }
    #pragma unroll
    for (int mi = 0; mi < 2; ++mi) {
        #pragma unroll
        for (int ks = 0; ks < 2; ++ks) {
            const int prow = w * 32 + mi * 16 + c;
            pfo[mi][ks] = prow * 64 + (((ks * 4 + quad) ^ (prow & 7)) << 3);
        }
        #pragma unroll
        for (int reg = 0; reg < 4; ++reg) {
            const int prow = w * 32 + mi * 16 + quad * 4 + reg;
            pwo[mi][reg] = prow * 64 + (((c >> 1) ^ (prow & 7)) * 8)
                           + ((c & 1) * 4);
        }
    }

    // ---- strength-reduced staging pointers (advance per kt) ----
    // K swizzle keyed (r>>2)&7 (QK^T reads row 4c+ni); V keyed r&7 (PV row ni*16+c)
    const ushort_t* kst[2]; const ushort_t* vst[2];
    #pragma unroll
    for (int rd = 0; rd < 2; ++rd) {
        const int t = (rd * 4 + w) * 64 + lane;
        const int r = t >> 3, sc = t & 7;
        kst[rd] = kp + (size_t)r * HD + (sc ^ ((r >> 2) & 7)) * 8;
        vst[rd] = vp + (size_t)r * SL + (sc ^ (r & 7)) * 8;
    }
    const int* mp = mask + b * SL + 4 * c;

    f32x4 oa[2][4];
    f32x4 oa1[2];                      // row-sum accumulators (replace l_s)
    const f32x4 zero = {0.f, 0.f, 0.f, 0.f};
    #pragma unroll
    for (int mi = 0; mi < 2; ++mi) {
        oa1[mi] = zero;
        #pragma unroll
        for (int ni = 0; ni < 4; ++ni) oa[mi][ni] = zero;
    }

    for (int kt = 0; kt < SL / 64; ++kt) {
        __syncthreads();
        load_lds16(kst[0], Ks + (0 * 4 + w) * 512);
        load_lds16(vst[0], Vs + (0 * 4 + w) * 512);
        load_lds16(kst[1], Ks + (1 * 4 + w) * 512);
        load_lds16(vst[1], Vs + (1 * 4 + w) * 512);
        kst[0] += 64 * HD; kst[1] += 64 * HD;
        vst[0] += 64;      vst[1] += 64;
        __syncthreads();

        // mask -> additive log2-domain bias, folded into the MFMA C-init
        const int4 mzv = *(const int4*)mp;
        mp += 64;
        float mb[4];
        mb[0] = (mzv.x == 0) ? -20000.f : 0.f;
        mb[1] = (mzv.y == 0) ? -20000.f : 0.f;
        mb[2] = (mzv.z == 0) ? -20000.f : 0.f;
        mb[3] = (mzv.w == 0) ? -20000.f : 0.f;

        // S = Q @ K^T + mask_bias, log2 domain. Col c of tile ni = key 4c+ni.
        f32x4 sf[2][4];
        #pragma unroll
        for (int mi = 0; mi < 2; ++mi)
            #pragma unroll
            for (int ni = 0; ni < 4; ++ni) {
                const f32x4 init = {mb[ni], mb[ni], mb[ni], mb[ni]};
                sf[mi][ni] = init;
            }
        __builtin_amdgcn_s_setprio(1);
        #pragma unroll
        for (int ni = 0; ni < 4; ++ni) {
            #pragma unroll
            for (int ks = 0; ks < 2; ++ks) {
                const short8 kf = *(const short8*)&Ks[kfo[ni][ks]];
                #pragma unroll
                for (int mi = 0; mi < 2; ++mi)
                    sf[mi][ni] = __builtin_amdgcn_mfma_f32_16x16x32_bf16(
                        qf[mi][ks], kf, sf[mi][ni], 0, 0, 0);
            }
        }
        __builtin_amdgcn_s_setprio(0);

        #pragma unroll
        for (int mi = 0; mi < 2; ++mi) {
            #pragma unroll
            for (int reg = 0; reg < 4; ++reg) {
                float p[4];
                #pragma unroll
                for (int ni = 0; ni < 4; ++ni)
                    p[ni] = __builtin_amdgcn_exp2f(sf[mi][ni][reg]);
                union { float f; uint_t u; } u0, u1, u2, u3;
                u0.f = p[0]; u1.f = p[1]; u2.f = p[2]; u3.f = p[3];
                uint2 pk;
                pk.x = __builtin_amdgcn_perm(u1.u, u0.u, 0x07060302u);
                pk.y = __builtin_amdgcn_perm(u3.u, u2.u, 0x07060302u);
                *(uint2*)&Ps[pwo[mi][reg]] = pk;
            }
        }
        // wave-local LDS round-trip: no barrier needed

        short8 pf[2][2];
        #pragma unroll
        for (int mi = 0; mi < 2; ++mi)
            #pragma unroll
            for (int ks = 0; ks < 2; ++ks)
                pf[mi][ks] = *(const short8*)&Ps[pfo[mi][ks]];
        __builtin_amdgcn_s_setprio(1);
        #pragma unroll
        for (int ni = 0; ni < 4; ++ni) {
            #pragma unroll
            for (int ks = 0; ks < 2; ++ks) {
                const short8 vf = *(const short8*)&Vs[vfo[ni][ks]];
                #pragma unroll
                for (int mi = 0; mi < 2; ++mi)
                    oa[mi][ni] = __builtin_amdgcn_mfma_f32_16x16x32_bf16(
                        pf[mi][ks], vf, oa[mi][ni], 0, 0, 0);
            }
        }
        // row-sum: l += P @ ones (constant B fragment, no LDS read)
        #pragma unroll
        for (int mi = 0; mi < 2; ++mi)
            #pragma unroll
            for (int ks = 0; ks < 2; ++ks)
                oa1[mi] = __builtin_amdgcn_mfma_f32_16x16x32_bf16(
                    pf[mi][ks], ones8, oa1[mi], 0, 0, 0);
        __builtin_amdgcn_s_setprio(0);
    }

    #pragma unroll
    for (int mi = 0; mi < 2; ++mi) {
        #pragma unroll
        for (int reg = 0; reg < 4; ++reg) {
            const float inv = 1.f / oa1[mi][reg];   // full row sum, every lane
            const int s_g = qt * 128 + w * 32 + mi * 16 + quad * 4 + reg;
            #pragma unroll
            for (int ni = 0; ni < 4; ++ni) {
                const int d = ni * 16 + c;
                ao[((size_t)(b * SL + s_g)) * HID + h * HD + d] =
                    (ushort_t)f2bf(oa[mi][ni][reg] * inv);
            }
        }
    }
}

// ---------------------------------------------------------------------------
// Output projection: out(fp32) = ao_bf @ Wo^T + bo. grid (8, 64).
// R10 simple version restored (R13's dbuf was null-to-negative: non-attn
// 184.6 -> 191.6 us).  XCD-banded remap kept.
// ---------------------------------------------------------------------------
__global__ __launch_bounds__(256) void out_mfma_kernel(
    const ushort_t* __restrict__ aob, const ushort_t* __restrict__ wob,
    const float* __restrict__ bo, float* __restrict__ out)
{
    __shared__ __align__(16) ushort_t As[128 * 64];
    __shared__ __align__(16) ushort_t Bs[128 * 64];

    const int flat = blockIdx.x + (blockIdx.y << 3);   // 0..511
    const int xcd = flat & 7, s = flat >> 3;
    const int m0 = ((xcd << 3) + (s >> 3)) * 128;
    const int n0 = (s & 7) * 128;

    f32x4 acc[4][4];
    const f32x4 zero = {0.f, 0.f, 0.f, 0.f};
    #pragma unroll
    for (int i = 0; i < 4; ++i)
        #pragma unroll
        for (int j = 0; j < 4; ++j) acc[i][j] = zero;

    gemm_core_bk64(aob, wob, m0, n0, As, Bs, acc);

    const int tid = threadIdx.x;
    const int w = tid >> 6, lane = tid & 63;
    const int wm = (w & 1) << 6, wn = (w >> 1) << 6;
    const int c = lane & 15, quad = lane >> 4;

    #pragma unroll
    for (int j = 0; j < 4; ++j) {
        const int n_g = n0 + wn + j * 16 + c;
        const float bj = bo[n_g];
        #pragma unroll
        for (int i = 0; i < 4; ++i) {
            const int mbase = m0 + wm + i * 16 + quad * 4;
            #pragma unroll
            for (int reg = 0; reg < 4; ++reg)
                out[(size_t)(mbase + reg) * HID + n_g] = acc[i][j][reg] + bj;
        }
    }
}

extern "C" void kernel_launch(void* const* d_in, const int* in_sizes, int n_in,
                              void* d_out, int out_size, void* d_ws, size_t ws_size,
                              hipStream_t stream)
{
    const float* x    = (const float*)d_in[0];
    const int*   mask = (const int*)d_in[1];
    const float* Wq   = (const float*)d_in[2];
    const float* bq   = (const float*)d_in[3];
    const float* Wk   = (const float*)d_in[4];
    const float* bk   = (const float*)d_in[5];
    const float* Wv   = (const float*)d_in[6];
    const float* bv   = (const float*)d_in[7];
    const float* Wo   = (const float*)d_in[8];
    const float* bo   = (const float*)d_in[9];
    float* out = (float*)d_out;

    ushort_t* p = (ushort_t*)d_ws;
    ushort_t* xb  = p; p += (size_t)MROWS * HID;
    ushort_t* wqb = p; p += (size_t)HID * HID;
    ushort_t* wkb = p; p += (size_t)HID * HID;
    ushort_t* wvb = p; p += (size_t)HID * HID;
    ushort_t* wob = p; p += (size_t)HID * HID;
    ushort_t* qb  = p; p += (size_t)MROWS * HID;
    ushort_t* kb  = p; p += (size_t)MROWS * HID;
    ushort_t* vtb = p; p += (size_t)MROWS * HID;
    ushort_t* aob = p; p += (size_t)MROWS * HID;

    cvt_bf16_kernel<<<dim3(512, 12), 256, 0, stream>>>(
        x, Wq, Wk, Wv, Wo, xb, wqb, wkb, wvb, wob);
    qkv_mfma_kernel<<<dim3(8, 64, 3), 256, 0, stream>>>(
        xb, wqb, wkb, wvb, bq, bk, bv, qb, kb, vtb);
    attn_mfma_kernel<<<dim3(16, 64), 256, 0, stream>>>(
        qb, kb, vtb, mask, aob);
    out_mfma_kernel<<<dim3(8, 64), 256, 0, stream>>>(
        aob, wob, bo, out);
}